// Round 15
// baseline (1383.069 us; speedup 1.0000x reference)
//
#include <hip/hip_runtime.h>
#include <math.h>

#define NT 1024

// ---- f64 LDS (doubles) ----
#define D_YCUR 0      // 64
#define D_KACC 64     // 64
#define D_T3   128    // 512 (also ic scratch)
#define D_VSIG 640    // 16*36
#define D_HID  1216   // 17*64
#define D_X0   2304   // 8
#define D_TOTAL 2312

// ---- f32 LDS ----
// pads: YB e+4*(e>>3); H1,H2,U-slices r+4*(r>>4) (a-stride 160)
#define F_YB 0        // 96
#define F_H1 96       // 160
#define F_D1 256      // 128
#define F_H2 384      // 160
#define F_D2 544      // 128
#define F_FB 672      // 512 linear
#define F_WM 1184     // 512 linear [8][64]
#define F_U1 1696     // 1280
#define F_U2 2976     // 1280
#define F_CM 4256     // 64
#define F_TOTAL 4320

static __device__ __forceinline__ double lipswish_d(double z, double* d) {
    double s = 1.0 / (1.0 + exp(-z));
    *d = 0.909 * s * (1.0 + z * (1.0 - s));
    return 0.909 * z * s;
}
static __device__ __forceinline__ float lipswish_f(float z, float* d) {
    float s = 1.0f / (1.0f + expf(-z));
    *d = 0.909f * s * (1.0f + z * (1.0f - s));
    return 0.909f * z * s;
}

template<int CTRL>
static __device__ __forceinline__ float dpp_mov_f(float v) {
    int xx = __builtin_amdgcn_update_dpp(0, __float_as_int(v), CTRL, 0xF, 0xF, false);
    return __int_as_float(xx);
}
static __device__ __forceinline__ float red8f(float v) {
    v += dpp_mov_f<0xB1>(v);
    v += dpp_mov_f<0x4E>(v);
    v += dpp_mov_f<0x141>(v);
    return v;
}
static __device__ __forceinline__ float red16f(float v) {
    v += dpp_mov_f<0xB1>(v);
    v += dpp_mov_f<0x4E>(v);
    v += dpp_mov_f<0x141>(v);
    v += dpp_mov_f<0x128>(v);   // row_ror:8
    return v;
}

extern "C" __global__ void __launch_bounds__(NT, 1)
ncde_solve(const float* __restrict__ x,
           const float* __restrict__ ic_w1, const float* __restrict__ ic_b1,
           const float* __restrict__ ic_w2, const float* __restrict__ ic_b2,
           const float* __restrict__ ic_w3, const float* __restrict__ ic_b3,
           const float* __restrict__ vf_w1, const float* __restrict__ vf_b1,
           const float* __restrict__ vf_w2, const float* __restrict__ vf_b2,
           const float* __restrict__ vf_w3, const float* __restrict__ vf_b3,
           const float* __restrict__ ro_w,  const float* __restrict__ ro_b,
           float* __restrict__ out)
{
    __shared__ double smd[D_TOTAL];
    __shared__ __align__(16) float smf[F_TOTAL];

    const int t = threadIdx.x;
    const int b = blockIdx.x;
    const float* xb = x + (size_t)b * (257 * 8);

    const int oq = (t >> 4) & 31;   // row-quad (128-row arrays): rows 4oq..4oq+3
    const int p16 = t & 15;         // K-slice within 16 lanes
    const int dh = t >> 9;          // half bit: P1/P2 skip, P5/P6 a-half
    const int mq = t >> 3;          // row-quad (512-row arrays): rows 4mq..4mq+3
    const int p8 = t & 7;           // K-slice within 8 lanes
    const int aT = mq >> 4;         // tangent for P7

    // ---- shared weight tiles (registers/AGPRs) ----
    float w1u[4][4];   // W1 rows 4oq..+3, cols 4p16..+3    (P1, P5)
    #pragma unroll
    for (int r = 0; r < 4; ++r) {
        float4 v = *reinterpret_cast<const float4*>(vf_w1 + (4 * oq + r) * 64 + 4 * p16);
        w1u[r][0] = v.x; w1u[r][1] = v.y; w1u[r][2] = v.z; w1u[r][3] = v.w;
    }
    float w2u[4][8];   // W2 rows 4oq..+3, cols 8p16..+7    (P2, P6)
    #pragma unroll
    for (int r = 0; r < 4; ++r) {
        const float4* s4 = reinterpret_cast<const float4*>(vf_w2 + (4 * oq + r) * 128 + 8 * p16);
        float4 v0 = s4[0], v1 = s4[1];
        w2u[r][0] = v0.x; w2u[r][1] = v0.y; w2u[r][2] = v0.z; w2u[r][3] = v0.w;
        w2u[r][4] = v1.x; w2u[r][5] = v1.y; w2u[r][6] = v1.z; w2u[r][7] = v1.w;
    }
    float w3q[4][16];  // W3 rows 4mq..+3, cols 16p8..+15   (P3, P7)
    #pragma unroll
    for (int r = 0; r < 4; ++r) {
        const float4* s4 = reinterpret_cast<const float4*>(vf_w3 + (size_t)(4 * mq + r) * 128 + 16 * p8);
        #pragma unroll
        for (int jj = 0; jj < 4; ++jj) {
            float4 v = s4[jj];
            w3q[r][4 * jj] = v.x; w3q[r][4 * jj + 1] = v.y;
            w3q[r][4 * jj + 2] = v.z; w3q[r][4 * jj + 3] = v.w;
        }
    }
    float b1q[4], b2q[4], b3q[4];
    #pragma unroll
    for (int r = 0; r < 4; ++r) {
        b1q[r] = vf_b1[4 * oq + r];
        b2q[r] = vf_b2[4 * oq + r];
        b3q[r] = vf_b3[4 * mq + r];
    }

    // ==== init: X0 + logsigs (f64) ====
    if (t < 8) smd[D_X0 + t] = (double)xb[t];
    if (t < 16) {
        const float* xr = xb + t * 16 * 8;
        double cum[8], area[28], prev[8];
        #pragma unroll
        for (int i = 0; i < 8; ++i) { cum[i] = 0.0; prev[i] = (double)xr[i]; }
        #pragma unroll
        for (int u = 0; u < 28; ++u) area[u] = 0.0;
        for (int k = 1; k <= 16; ++k) {
            double dx[8];
            #pragma unroll
            for (int i = 0; i < 8; ++i) {
                double c = (double)xr[k * 8 + i];
                dx[i] = c - prev[i];
                prev[i] = c;
            }
            #pragma unroll
            for (int i = 0; i < 7; ++i) {
                #pragma unroll
                for (int j = i + 1; j < 8; ++j) {
                    int u = 7 * i - (i * (i - 1)) / 2 + (j - i - 1);
                    area[u] += 0.5 * (cum[i] * dx[j] - cum[j] * dx[i]);
                }
            }
            #pragma unroll
            for (int i = 0; i < 8; ++i) cum[i] += dx[i];
        }
        #pragma unroll
        for (int i = 0; i < 8; ++i) smd[D_VSIG + t * 36 + i] = cum[i];
        #pragma unroll
        for (int u = 0; u < 28; ++u) smd[D_VSIG + t * 36 + 8 + u] = area[u];
    }
    __syncthreads();

    // ==== ic MLP (f64; scratch in D_T3) ====
    if (t < 128) {
        double acc = (double)ic_b1[t];
        #pragma unroll
        for (int e = 0; e < 8; ++e) acc += (double)ic_w1[t * 8 + e] * smd[D_X0 + e];
        double d;
        smd[D_T3 + t] = lipswish_d(acc, &d);
    }
    __syncthreads();
    if (t < 128) {
        const float4* wr = reinterpret_cast<const float4*>(ic_w2 + t * 128);
        double a0 = 0.0, a1 = 0.0, a2 = 0.0, a3 = 0.0;
        #pragma unroll
        for (int k = 0; k < 32; ++k) {
            float4 wv = wr[k];
            double2 h0 = *reinterpret_cast<const double2*>(&smd[D_T3 + 4 * k]);
            double2 h1 = *reinterpret_cast<const double2*>(&smd[D_T3 + 4 * k + 2]);
            a0 += (double)wv.x * h0.x; a1 += (double)wv.y * h0.y;
            a2 += (double)wv.z * h1.x; a3 += (double)wv.w * h1.y;
        }
        double d;
        smd[D_T3 + 128 + t] = lipswish_d((double)ic_b2[t] + (a0 + a2) + (a1 + a3), &d);
    }
    __syncthreads();
    if (t < 64) {
        const float4* wr = reinterpret_cast<const float4*>(ic_w3 + t * 128);
        double a0 = 0.0, a1 = 0.0, a2 = 0.0, a3 = 0.0;
        #pragma unroll
        for (int k = 0; k < 32; ++k) {
            float4 wv = wr[k];
            double2 h0 = *reinterpret_cast<const double2*>(&smd[D_T3 + 128 + 4 * k]);
            double2 h1 = *reinterpret_cast<const double2*>(&smd[D_T3 + 128 + 4 * k + 2]);
            a0 += (double)wv.x * h0.x; a1 += (double)wv.y * h0.y;
            a2 += (double)wv.z * h1.x; a3 += (double)wv.w * h1.y;
        }
        double y0 = (double)ic_b3[t] + (a0 + a2) + (a1 + a3);
        smd[D_YCUR + t] = y0;
        smd[D_HID + t]  = y0;
        smf[F_YB + t + 4 * (t >> 3)] = (float)y0;
        int a = t >> 3, bb = t & 7;
        double cv = 0.0;
        if (a != bb) {
            int i = a < bb ? a : bb;
            int j = a < bb ? bb : a;
            int pidx = 7 * i - (i * (i - 1)) / 2 + (j - i - 1);
            double vv = smd[D_VSIG + 8 + pidx];
            cv = (a > bb) ? vv : -vv;
        }
        smf[F_CM + t] = (float)cv;
    }
    __syncthreads();

    // ==== RK4 scan ====
    for (int w = 0; w < 16; ++w) {
        for (int stage = 0; stage < 4; ++stage) {
            // ---- P1: L1 f32, 4 rows/thread, waves 0-7 only ----
            if (dh == 0) {
                float4 yv = *reinterpret_cast<const float4*>(&smf[F_YB + 4 * p16 + 4 * (p16 >> 1)]);
                float acc0 = w1u[0][0] * yv.x + w1u[0][1] * yv.y + w1u[0][2] * yv.z + w1u[0][3] * yv.w;
                float acc1 = w1u[1][0] * yv.x + w1u[1][1] * yv.y + w1u[1][2] * yv.z + w1u[1][3] * yv.w;
                float acc2 = w1u[2][0] * yv.x + w1u[2][1] * yv.y + w1u[2][2] * yv.z + w1u[2][3] * yv.w;
                float acc3 = w1u[3][0] * yv.x + w1u[3][1] * yv.y + w1u[3][2] * yv.z + w1u[3][3] * yv.w;
                acc0 = red16f(acc0); acc1 = red16f(acc1);
                acc2 = red16f(acc2); acc3 = red16f(acc3);
                if (p16 == 0) {
                    float4 hv, dv;
                    hv.x = lipswish_f(acc0 + b1q[0], &dv.x);
                    hv.y = lipswish_f(acc1 + b1q[1], &dv.y);
                    hv.z = lipswish_f(acc2 + b1q[2], &dv.z);
                    hv.w = lipswish_f(acc3 + b1q[3], &dv.w);
                    *reinterpret_cast<float4*>(&smf[F_H1 + 4 * oq + 4 * (oq >> 2)]) = hv;
                    *reinterpret_cast<float4*>(&smf[F_D1 + 4 * oq]) = dv;
                }
            }
            __syncthreads();
            // ---- P2: L2 f32, 4 rows/thread, waves 0-7 only ----
            if (dh == 0) {
                int hb = 8 * p16 + 4 * (p16 >> 1);
                float4 h0 = *reinterpret_cast<const float4*>(&smf[F_H1 + hb]);
                float4 h1 = *reinterpret_cast<const float4*>(&smf[F_H1 + hb + 4]);
                float acc[4];
                #pragma unroll
                for (int r = 0; r < 4; ++r) {
                    acc[r] = w2u[r][0] * h0.x + w2u[r][1] * h0.y + w2u[r][2] * h0.z + w2u[r][3] * h0.w
                           + w2u[r][4] * h1.x + w2u[r][5] * h1.y + w2u[r][6] * h1.z + w2u[r][7] * h1.w;
                    acc[r] = red16f(acc[r]);
                }
                if (p16 == 0) {
                    float4 hv, dv;
                    hv.x = lipswish_f(acc[0] + b2q[0], &dv.x);
                    hv.y = lipswish_f(acc[1] + b2q[1], &dv.y);
                    hv.z = lipswish_f(acc[2] + b2q[2], &dv.z);
                    hv.w = lipswish_f(acc[3] + b2q[3], &dv.w);
                    *reinterpret_cast<float4*>(&smf[F_H2 + 4 * oq + 4 * (oq >> 2)]) = hv;
                    *reinterpret_cast<float4*>(&smf[F_D2 + 4 * oq]) = dv;
                }
            }
            __syncthreads();
            // ---- P3: L3 f32, 4 rows/thread ----
            float Fq[4] = {0.0f, 0.0f, 0.0f, 0.0f};
            {
                float acc[4] = {0.0f, 0.0f, 0.0f, 0.0f};
                #pragma unroll
                for (int k = 0; k < 4; ++k) {
                    float4 hv = *reinterpret_cast<const float4*>(&smf[F_H2 + 20 * p8 + 4 * k]);
                    #pragma unroll
                    for (int r = 0; r < 4; ++r)
                        acc[r] += w3q[r][4 * k] * hv.x + w3q[r][4 * k + 1] * hv.y
                                + w3q[r][4 * k + 2] * hv.z + w3q[r][4 * k + 3] * hv.w;
                }
                #pragma unroll
                for (int r = 0; r < 4; ++r) acc[r] = red8f(acc[r]);
                if (p8 == 0) {
                    float4 fv;
                    Fq[0] = fv.x = tanhf(acc[0] + b3q[0]);
                    Fq[1] = fv.y = tanhf(acc[1] + b3q[1]);
                    Fq[2] = fv.z = tanhf(acc[2] + b3q[2]);
                    Fq[3] = fv.w = tanhf(acc[3] + b3q[3]);
                    *reinterpret_cast<float4*>(&smf[F_FB + 4 * mq]) = fv;
                }
            }
            __syncthreads();
            // ---- P4: WM f32, 2 waves, float4 ----
            if (t < 128) {
                int a = t >> 4, eq = t & 15;
                float cm[8];
                #pragma unroll
                for (int bb = 0; bb < 8; ++bb) cm[bb] = smf[F_CM + a * 8 + bb];
                float4 s; s.x = 0.0f; s.y = 0.0f; s.z = 0.0f; s.w = 0.0f;
                #pragma unroll
                for (int bb = 0; bb < 8; ++bb) {
                    float4 fv = *reinterpret_cast<const float4*>(&smf[F_FB + bb * 64 + 4 * eq]);
                    s.x += cm[bb] * fv.x; s.y += cm[bb] * fv.y;
                    s.z += cm[bb] * fv.z; s.w += cm[bb] * fv.w;
                }
                *reinterpret_cast<float4*>(&smf[F_WM + a * 64 + 4 * eq]) = s;
            }
            __syncthreads();
            // ---- P5: U1 f32, 4 rows × 4 tangents/thread ----
            {
                #pragma unroll
                for (int ai = 0; ai < 4; ++ai) {
                    int a = 4 * dh + ai;
                    float4 mv = *reinterpret_cast<const float4*>(&smf[F_WM + a * 64 + 4 * p16]);
                    float acc[4];
                    #pragma unroll
                    for (int r = 0; r < 4; ++r) {
                        acc[r] = w1u[r][0] * mv.x + w1u[r][1] * mv.y
                               + w1u[r][2] * mv.z + w1u[r][3] * mv.w;
                        acc[r] = red16f(acc[r]);
                    }
                    if (p16 == 0) {
                        float4 dv = *reinterpret_cast<const float4*>(&smf[F_D1 + 4 * oq]);
                        float4 uv;
                        uv.x = acc[0] * dv.x; uv.y = acc[1] * dv.y;
                        uv.z = acc[2] * dv.z; uv.w = acc[3] * dv.w;
                        *reinterpret_cast<float4*>(&smf[F_U1 + a * 160 + 4 * oq + 4 * (oq >> 2)]) = uv;
                    }
                }
            }
            __syncthreads();
            // ---- P6: U2 f32, 4 rows × 4 tangents/thread ----
            {
                int ib = 8 * p16 + 4 * (p16 >> 1);
                #pragma unroll
                for (int ai = 0; ai < 4; ++ai) {
                    int a = 4 * dh + ai;
                    float4 u0 = *reinterpret_cast<const float4*>(&smf[F_U1 + a * 160 + ib]);
                    float4 u1 = *reinterpret_cast<const float4*>(&smf[F_U1 + a * 160 + ib + 4]);
                    float acc[4];
                    #pragma unroll
                    for (int r = 0; r < 4; ++r) {
                        acc[r] = w2u[r][0] * u0.x + w2u[r][1] * u0.y + w2u[r][2] * u0.z + w2u[r][3] * u0.w
                               + w2u[r][4] * u1.x + w2u[r][5] * u1.y + w2u[r][6] * u1.z + w2u[r][7] * u1.w;
                        acc[r] = red16f(acc[r]);
                    }
                    if (p16 == 0) {
                        float4 dv = *reinterpret_cast<const float4*>(&smf[F_D2 + 4 * oq]);
                        float4 uv;
                        uv.x = acc[0] * dv.x; uv.y = acc[1] * dv.y;
                        uv.z = acc[2] * dv.z; uv.w = acc[3] * dv.w;
                        *reinterpret_cast<float4*>(&smf[F_U2 + a * 160 + 4 * oq + 4 * (oq >> 2)]) = uv;
                    }
                }
            }
            __syncthreads();
            // ---- P7: T3, 4 rows/thread (f32 dot, f64 finish) ----
            {
                float acc[4] = {0.0f, 0.0f, 0.0f, 0.0f};
                #pragma unroll
                for (int k = 0; k < 4; ++k) {
                    float4 uv = *reinterpret_cast<const float4*>(&smf[F_U2 + aT * 160 + 20 * p8 + 4 * k]);
                    #pragma unroll
                    for (int r = 0; r < 4; ++r)
                        acc[r] += w3q[r][4 * k] * uv.x + w3q[r][4 * k + 1] * uv.y
                                + w3q[r][4 * k + 2] * uv.z + w3q[r][4 * k + 3] * uv.w;
                }
                #pragma unroll
                for (int r = 0; r < 4; ++r) acc[r] = red8f(acc[r]);
                if (p8 == 0) {
                    double va = smd[D_VSIG + w * 36 + aT];
                    double2 t0, t1;
                    t0.x = va * (double)Fq[0] + (1.0 - (double)Fq[0] * Fq[0]) * (double)acc[0];
                    t0.y = va * (double)Fq[1] + (1.0 - (double)Fq[1] * Fq[1]) * (double)acc[1];
                    t1.x = va * (double)Fq[2] + (1.0 - (double)Fq[2] * Fq[2]) * (double)acc[2];
                    t1.y = va * (double)Fq[3] + (1.0 - (double)Fq[3] * Fq[3]) * (double)acc[3];
                    *reinterpret_cast<double2*>(&smd[D_T3 + 4 * mq])     = t0;
                    *reinterpret_cast<double2*>(&smd[D_T3 + 4 * mq + 2]) = t1;
                }
            }
            __syncthreads();
            // ---- P8: combine + RK4 glue f64 (+ next CMAT) ----
            if (t < 64) {
                double g = 0.0;
                #pragma unroll
                for (int a = 0; a < 8; ++a) g += smd[D_T3 + a * 64 + t];
                double y = smd[D_YCUR + t];
                int yp = F_YB + t + 4 * (t >> 3);
                if (stage == 0)      { smd[D_KACC + t] = g;        smf[yp] = (float)(y + 0.5 * g); }
                else if (stage == 1) { smd[D_KACC + t] += 2.0 * g; smf[yp] = (float)(y + 0.5 * g); }
                else if (stage == 2) { smd[D_KACC + t] += 2.0 * g; smf[yp] = (float)(y + g); }
                else {
                    double yn = y + (smd[D_KACC + t] + g) * (1.0 / 6.0);
                    smd[D_YCUR + t] = yn;
                    smf[yp] = (float)yn;
                    smd[D_HID + (w + 1) * 64 + t] = yn;
                }
            } else if (t < 128 && stage == 3 && w < 15) {
                int idx = t - 64;
                int a = idx >> 3, bb = idx & 7;
                double cv = 0.0;
                if (a != bb) {
                    int i = a < bb ? a : bb;
                    int j = a < bb ? bb : a;
                    int pidx = 7 * i - (i * (i - 1)) / 2 + (j - i - 1);
                    double vv = smd[D_VSIG + (w + 1) * 36 + 8 + pidx];
                    cv = (a > bb) ? vv : -vv;
                }
                smf[F_CM + idx] = (float)cv;
            }
            __syncthreads();
        }
    }

    // ==== readout (f64) ====
    for (int idx = t; idx < 544; idx += NT) {
        int s = idx >> 5, oo = idx & 31;
        double acc = (double)ro_b[oo];
        const float* wr = ro_w + oo * 64;
        const double* hr = &smd[D_HID + s * 64];
        #pragma unroll
        for (int d = 0; d < 64; ++d) acc += (double)wr[d] * hr[d];
        out[(size_t)b * 544 + idx] = (float)acc;
    }
}

extern "C" void kernel_launch(void* const* d_in, const int* in_sizes, int n_in,
                              void* d_out, int out_size, void* d_ws, size_t ws_size,
                              hipStream_t stream) {
    const float* x     = (const float*)d_in[0];
    const float* ic_w1 = (const float*)d_in[1];
    const float* ic_b1 = (const float*)d_in[2];
    const float* ic_w2 = (const float*)d_in[3];
    const float* ic_b2 = (const float*)d_in[4];
    const float* ic_w3 = (const float*)d_in[5];
    const float* ic_b3 = (const float*)d_in[6];
    const float* vf_w1 = (const float*)d_in[7];
    const float* vf_b1 = (const float*)d_in[8];
    const float* vf_w2 = (const float*)d_in[9];
    const float* vf_b2 = (const float*)d_in[10];
    const float* vf_w3 = (const float*)d_in[11];
    const float* vf_b3 = (const float*)d_in[12];
    const float* ro_w  = (const float*)d_in[13];
    const float* ro_b  = (const float*)d_in[14];
    float* out = (float*)d_out;

    int B = in_sizes[0] / (257 * 8);
    hipLaunchKernelGGL(ncde_solve, dim3(B), dim3(NT), 0, stream,
                       x, ic_w1, ic_b1, ic_w2, ic_b2, ic_w3, ic_b3,
                       vf_w1, vf_b1, vf_w2, vf_b2, vf_w3, vf_b3, ro_w, ro_b, out);
}

// Round 16
// 622.635 us; speedup vs baseline: 2.2213x; 2.2213x over previous
//
#include <hip/hip_runtime.h>
#include <math.h>

#define NT 1024

// ---- f64 LDS (doubles) ----
#define D_YCUR 0      // 64
#define D_KACC 64     // 64
#define D_T3   128    // 512 (also ic scratch)
#define D_VSIG 640    // 16*36
#define D_HID  1216   // 17*64
#define D_X0   2304   // 8
#define D_TOTAL 2312

// ---- f32 LDS ----
// pads: YB e+4*(e>>3); H1,H2,U-slices r+4*(r>>4) (a-stride 160)
#define F_YB 0        // 96
#define F_H1 96       // 160
#define F_D1 256      // 128
#define F_H2 384      // 160
#define F_D2 544      // 128
#define F_FB 672      // 512 linear
#define F_WM 1184     // 512 linear [8][64]
#define F_U1 1696     // 1280
#define F_U2 2976     // 1280
#define F_CM 4256     // 64
#define F_TOTAL 4320

static __device__ __forceinline__ double lipswish_d(double z, double* d) {
    double s = 1.0 / (1.0 + exp(-z));
    *d = 0.909 * s * (1.0 + z * (1.0 - s));
    return 0.909 * z * s;
}
static __device__ __forceinline__ float lipswish_f(float z, float* d) {
    float s = 1.0f / (1.0f + expf(-z));
    *d = 0.909f * s * (1.0f + z * (1.0f - s));
    return 0.909f * z * s;
}

template<int CTRL>
static __device__ __forceinline__ float dpp_mov_f(float v) {
    int xx = __builtin_amdgcn_update_dpp(0, __float_as_int(v), CTRL, 0xF, 0xF, false);
    return __int_as_float(xx);
}
static __device__ __forceinline__ float red8f(float v) {
    v += dpp_mov_f<0xB1>(v);
    v += dpp_mov_f<0x4E>(v);
    v += dpp_mov_f<0x141>(v);
    return v;
}
static __device__ __forceinline__ float red16f(float v) {
    v += dpp_mov_f<0xB1>(v);
    v += dpp_mov_f<0x4E>(v);
    v += dpp_mov_f<0x141>(v);
    v += dpp_mov_f<0x128>(v);   // row_ror:8
    return v;
}
static __device__ __forceinline__ float red4f(float v) {
    v += dpp_mov_f<0xB1>(v);
    v += dpp_mov_f<0x4E>(v);
    return v;
}
static __device__ __forceinline__ float red2f(float v) {
    return v + dpp_mov_f<0xB1>(v);
}

extern "C" __global__ void __launch_bounds__(NT, 1)
ncde_solve(const float* __restrict__ x,
           const float* __restrict__ ic_w1, const float* __restrict__ ic_b1,
           const float* __restrict__ ic_w2, const float* __restrict__ ic_b2,
           const float* __restrict__ ic_w3, const float* __restrict__ ic_b3,
           const float* __restrict__ vf_w1, const float* __restrict__ vf_b1,
           const float* __restrict__ vf_w2, const float* __restrict__ vf_b2,
           const float* __restrict__ vf_w3, const float* __restrict__ vf_b3,
           const float* __restrict__ ro_w,  const float* __restrict__ ro_b,
           float* __restrict__ out)
{
    __shared__ double smd[D_TOTAL];
    __shared__ __align__(16) float smf[F_TOTAL];

    const int t = threadIdx.x;
    const int b = blockIdx.x;
    const float* xb = x + (size_t)b * (257 * 8);

    const int o8 = t >> 3, p8 = t & 7;      // P1/P2
    const int o16 = t >> 4, p16 = t & 15;   // P5/P6 (rows o16, o16+64)
    const int m = t >> 2, q = t & 3;        // P3/P7 (rows 2m,2m+1)
    const int aT = t >> 7;                  // tangent index

    // ---- weights in f32 registers (R14 tiling — proven no-spill) ----
    float w1f[8];    // P1: row o8, cols [8p8, 8p8+8)
    {
        const float4* s4 = reinterpret_cast<const float4*>(vf_w1 + o8 * 64 + 8 * p8);
        float4 v0 = s4[0], v1 = s4[1];
        w1f[0] = v0.x; w1f[1] = v0.y; w1f[2] = v0.z; w1f[3] = v0.w;
        w1f[4] = v1.x; w1f[5] = v1.y; w1f[6] = v1.z; w1f[7] = v1.w;
    }
    float w2f[16];   // P2: row o8, cols [16p8, 16p8+16)
    {
        const float4* s4 = reinterpret_cast<const float4*>(vf_w2 + o8 * 128 + 16 * p8);
        #pragma unroll
        for (int jj = 0; jj < 4; ++jj) {
            float4 v = s4[jj];
            w2f[4 * jj] = v.x; w2f[4 * jj + 1] = v.y;
            w2f[4 * jj + 2] = v.z; w2f[4 * jj + 3] = v.w;
        }
    }
    float w1u[2][4]; // P5: rows o16,o16+64, cols [4p16,4p16+4)
    {
        float4 a = *reinterpret_cast<const float4*>(vf_w1 + o16 * 64 + 4 * p16);
        float4 c = *reinterpret_cast<const float4*>(vf_w1 + (o16 + 64) * 64 + 4 * p16);
        w1u[0][0] = a.x; w1u[0][1] = a.y; w1u[0][2] = a.z; w1u[0][3] = a.w;
        w1u[1][0] = c.x; w1u[1][1] = c.y; w1u[1][2] = c.z; w1u[1][3] = c.w;
    }
    float w2u[2][8]; // P6: rows o16,o16+64, cols [8p16,8p16+8)
    {
        const float4* sa = reinterpret_cast<const float4*>(vf_w2 + o16 * 128 + 8 * p16);
        const float4* sb = reinterpret_cast<const float4*>(vf_w2 + (o16 + 64) * 128 + 8 * p16);
        float4 a0 = sa[0], a1 = sa[1], c0 = sb[0], c1 = sb[1];
        w2u[0][0] = a0.x; w2u[0][1] = a0.y; w2u[0][2] = a0.z; w2u[0][3] = a0.w;
        w2u[0][4] = a1.x; w2u[0][5] = a1.y; w2u[0][6] = a1.z; w2u[0][7] = a1.w;
        w2u[1][0] = c0.x; w2u[1][1] = c0.y; w2u[1][2] = c0.z; w2u[1][3] = c0.w;
        w2u[1][4] = c1.x; w2u[1][5] = c1.y; w2u[1][6] = c1.z; w2u[1][7] = c1.w;
    }
    float w3a[32], w3b[32]; // P3/P7: rows 2m,2m+1, cols [32q,32q+32)
    {
        const float4* sa = reinterpret_cast<const float4*>(vf_w3 + (size_t)(2 * m) * 128 + 32 * q);
        const float4* sb = reinterpret_cast<const float4*>(vf_w3 + (size_t)(2 * m + 1) * 128 + 32 * q);
        #pragma unroll
        for (int jj = 0; jj < 8; ++jj) {
            float4 va = sa[jj], vb = sb[jj];
            w3a[4 * jj] = va.x; w3a[4 * jj + 1] = va.y; w3a[4 * jj + 2] = va.z; w3a[4 * jj + 3] = va.w;
            w3b[4 * jj] = vb.x; w3b[4 * jj + 1] = vb.y; w3b[4 * jj + 2] = vb.z; w3b[4 * jj + 3] = vb.w;
        }
    }
    const float b1o = vf_b1[o8];
    const float b2o = vf_b2[o8];
    const float b3a = vf_b3[2 * m];
    const float b3b = vf_b3[2 * m + 1];

    // ==== init: X0 + logsigs (f64) ====
    if (t < 8) smd[D_X0 + t] = (double)xb[t];
    if (t < 16) {
        const float* xr = xb + t * 16 * 8;
        double cum[8], area[28], prev[8];
        #pragma unroll
        for (int i = 0; i < 8; ++i) { cum[i] = 0.0; prev[i] = (double)xr[i]; }
        #pragma unroll
        for (int u = 0; u < 28; ++u) area[u] = 0.0;
        for (int k = 1; k <= 16; ++k) {
            double dx[8];
            #pragma unroll
            for (int i = 0; i < 8; ++i) {
                double c = (double)xr[k * 8 + i];
                dx[i] = c - prev[i];
                prev[i] = c;
            }
            #pragma unroll
            for (int i = 0; i < 7; ++i) {
                #pragma unroll
                for (int j = i + 1; j < 8; ++j) {
                    int u = 7 * i - (i * (i - 1)) / 2 + (j - i - 1);
                    area[u] += 0.5 * (cum[i] * dx[j] - cum[j] * dx[i]);
                }
            }
            #pragma unroll
            for (int i = 0; i < 8; ++i) cum[i] += dx[i];
        }
        #pragma unroll
        for (int i = 0; i < 8; ++i) smd[D_VSIG + t * 36 + i] = cum[i];
        #pragma unroll
        for (int u = 0; u < 28; ++u) smd[D_VSIG + t * 36 + 8 + u] = area[u];
    }
    __syncthreads();

    // ==== ic MLP (f64; scratch in D_T3) ====
    if (t < 128) {
        double acc = (double)ic_b1[t];
        #pragma unroll
        for (int e = 0; e < 8; ++e) acc += (double)ic_w1[t * 8 + e] * smd[D_X0 + e];
        double d;
        smd[D_T3 + t] = lipswish_d(acc, &d);
    }
    __syncthreads();
    if (t < 128) {
        const float4* wr = reinterpret_cast<const float4*>(ic_w2 + t * 128);
        double a0 = 0.0, a1 = 0.0, a2 = 0.0, a3 = 0.0;
        #pragma unroll
        for (int k = 0; k < 32; ++k) {
            float4 wv = wr[k];
            double2 h0 = *reinterpret_cast<const double2*>(&smd[D_T3 + 4 * k]);
            double2 h1 = *reinterpret_cast<const double2*>(&smd[D_T3 + 4 * k + 2]);
            a0 += (double)wv.x * h0.x; a1 += (double)wv.y * h0.y;
            a2 += (double)wv.z * h1.x; a3 += (double)wv.w * h1.y;
        }
        double d;
        smd[D_T3 + 128 + t] = lipswish_d((double)ic_b2[t] + (a0 + a2) + (a1 + a3), &d);
    }
    __syncthreads();
    if (t < 64) {
        const float4* wr = reinterpret_cast<const float4*>(ic_w3 + t * 128);
        double a0 = 0.0, a1 = 0.0, a2 = 0.0, a3 = 0.0;
        #pragma unroll
        for (int k = 0; k < 32; ++k) {
            float4 wv = wr[k];
            double2 h0 = *reinterpret_cast<const double2*>(&smd[D_T3 + 128 + 4 * k]);
            double2 h1 = *reinterpret_cast<const double2*>(&smd[D_T3 + 128 + 4 * k + 2]);
            a0 += (double)wv.x * h0.x; a1 += (double)wv.y * h0.y;
            a2 += (double)wv.z * h1.x; a3 += (double)wv.w * h1.y;
        }
        double y0 = (double)ic_b3[t] + (a0 + a2) + (a1 + a3);
        smd[D_YCUR + t] = y0;
        smd[D_HID + t]  = y0;
        smf[F_YB + t + 4 * (t >> 3)] = (float)y0;
        int a = t >> 3, bb = t & 7;
        double cv = 0.0;
        if (a != bb) {
            int i = a < bb ? a : bb;
            int j = a < bb ? bb : a;
            int pidx = 7 * i - (i * (i - 1)) / 2 + (j - i - 1);
            double vv = smd[D_VSIG + 8 + pidx];
            cv = (a > bb) ? vv : -vv;
        }
        smf[F_CM + t] = (float)cv;
    }
    __syncthreads();

    // ==== RK4 scan ====
    for (int w = 0; w < 16; ++w) {
        for (int stage = 0; stage < 4; ++stage) {
            // ---- P1: L1 f32 ----
            {
                float4 y0 = *reinterpret_cast<const float4*>(&smf[F_YB + 12 * p8]);
                float4 y1 = *reinterpret_cast<const float4*>(&smf[F_YB + 12 * p8 + 4]);
                float acc = w1f[0] * y0.x + w1f[1] * y0.y + w1f[2] * y0.z + w1f[3] * y0.w
                          + w1f[4] * y1.x + w1f[5] * y1.y + w1f[6] * y1.z + w1f[7] * y1.w;
                acc = red8f(acc);
                if (p8 == 0) {
                    float d;
                    smf[F_H1 + o8 + 4 * (o8 >> 4)] = lipswish_f(acc + b1o, &d);
                    smf[F_D1 + o8] = d;
                }
            }
            __syncthreads();
            // ---- P2: L2 f32 ----
            {
                const float4* hv = reinterpret_cast<const float4*>(&smf[F_H1 + 20 * p8]);
                float4 h0 = hv[0], h1 = hv[1], h2 = hv[2], h3 = hv[3];
                float a0 = w2f[0] * h0.x + w2f[1] * h0.y + w2f[2] * h0.z + w2f[3] * h0.w
                         + w2f[4] * h1.x + w2f[5] * h1.y + w2f[6] * h1.z + w2f[7] * h1.w;
                float a1 = w2f[8] * h2.x + w2f[9] * h2.y + w2f[10] * h2.z + w2f[11] * h2.w
                         + w2f[12] * h3.x + w2f[13] * h3.y + w2f[14] * h3.z + w2f[15] * h3.w;
                float acc = red8f(a0 + a1);
                if (p8 == 0) {
                    float d;
                    smf[F_H2 + o8 + 4 * (o8 >> 4)] = lipswish_f(acc + b2o, &d);
                    smf[F_D2 + o8] = d;
                }
            }
            __syncthreads();
            // ---- P3: L3 f32, dual-row q4 ----
            float F0 = 0.0f, F1 = 0.0f;
            {
                float a0 = 0.0f, a1 = 0.0f;
                #pragma unroll
                for (int jj = 0; jj < 8; ++jj) {
                    float4 hv = *reinterpret_cast<const float4*>(
                        &smf[F_H2 + 40 * q + 4 * jj + 4 * (jj >> 2)]);
                    a0 += w3a[4 * jj] * hv.x + w3a[4 * jj + 1] * hv.y
                        + w3a[4 * jj + 2] * hv.z + w3a[4 * jj + 3] * hv.w;
                    a1 += w3b[4 * jj] * hv.x + w3b[4 * jj + 1] * hv.y
                        + w3b[4 * jj + 2] * hv.z + w3b[4 * jj + 3] * hv.w;
                }
                a0 = red4f(a0);
                a1 = red4f(a1);
                if (q == 0) {
                    F0 = tanhf(a0 + b3a);
                    F1 = tanhf(a1 + b3b);
                    float2 fv; fv.x = F0; fv.y = F1;
                    *reinterpret_cast<float2*>(&smf[F_FB + 2 * m]) = fv;
                }
            }
            __syncthreads();
            // ---- P4: WM f32, 2 waves, float4 ----
            if (t < 128) {
                int a = t >> 4, eq = t & 15;
                float cm[8];
                #pragma unroll
                for (int bb = 0; bb < 8; ++bb) cm[bb] = smf[F_CM + a * 8 + bb];
                float4 s; s.x = 0.0f; s.y = 0.0f; s.z = 0.0f; s.w = 0.0f;
                #pragma unroll
                for (int bb = 0; bb < 8; ++bb) {
                    float4 fv = *reinterpret_cast<const float4*>(&smf[F_FB + bb * 64 + 4 * eq]);
                    s.x += cm[bb] * fv.x; s.y += cm[bb] * fv.y;
                    s.z += cm[bb] * fv.z; s.w += cm[bb] * fv.w;
                }
                *reinterpret_cast<float4*>(&smf[F_WM + a * 64 + 4 * eq]) = s;
            }
            __syncthreads();
            // ---- P5: U1 f32, batched-ILP halves of 4 tangents ----
            {
                float d1a = smf[F_D1 + o16], d1b = smf[F_D1 + o16 + 64];
                int ob = F_U1 + o16 + 4 * (o16 >> 4);
                #pragma unroll
                for (int half = 0; half < 2; ++half) {
                    float a0[4], a1[4];
                    #pragma unroll
                    for (int ai = 0; ai < 4; ++ai) {
                        int a = 4 * half + ai;
                        float4 mv = *reinterpret_cast<const float4*>(&smf[F_WM + a * 64 + 4 * p16]);
                        a0[ai] = w1u[0][0] * mv.x + w1u[0][1] * mv.y + w1u[0][2] * mv.z + w1u[0][3] * mv.w;
                        a1[ai] = w1u[1][0] * mv.x + w1u[1][1] * mv.y + w1u[1][2] * mv.z + w1u[1][3] * mv.w;
                    }
                    #pragma unroll
                    for (int ai = 0; ai < 4; ++ai) {
                        a0[ai] = red16f(a0[ai]);
                        a1[ai] = red16f(a1[ai]);
                    }
                    if (p16 == 0) {
                        #pragma unroll
                        for (int ai = 0; ai < 4; ++ai) {
                            int a = 4 * half + ai;
                            smf[ob + a * 160]      = a0[ai] * d1a;
                            smf[ob + a * 160 + 80] = a1[ai] * d1b;
                        }
                    }
                }
            }
            __syncthreads();
            // ---- P6: U2 f32, batched-ILP halves of 4 tangents ----
            {
                float d2a = smf[F_D2 + o16], d2b = smf[F_D2 + o16 + 64];
                int ib = 8 * p16 + 4 * (p16 >> 1);
                int ob = F_U2 + o16 + 4 * (o16 >> 4);
                #pragma unroll
                for (int half = 0; half < 2; ++half) {
                    float a0[4], a1[4];
                    #pragma unroll
                    for (int ai = 0; ai < 4; ++ai) {
                        int a = 4 * half + ai;
                        float4 u0 = *reinterpret_cast<const float4*>(&smf[F_U1 + a * 160 + ib]);
                        float4 u1 = *reinterpret_cast<const float4*>(&smf[F_U1 + a * 160 + ib + 4]);
                        a0[ai] = w2u[0][0] * u0.x + w2u[0][1] * u0.y + w2u[0][2] * u0.z + w2u[0][3] * u0.w
                               + w2u[0][4] * u1.x + w2u[0][5] * u1.y + w2u[0][6] * u1.z + w2u[0][7] * u1.w;
                        a1[ai] = w2u[1][0] * u0.x + w2u[1][1] * u0.y + w2u[1][2] * u0.z + w2u[1][3] * u0.w
                               + w2u[1][4] * u1.x + w2u[1][5] * u1.y + w2u[1][6] * u1.z + w2u[1][7] * u1.w;
                    }
                    #pragma unroll
                    for (int ai = 0; ai < 4; ++ai) {
                        a0[ai] = red16f(a0[ai]);
                        a1[ai] = red16f(a1[ai]);
                    }
                    if (p16 == 0) {
                        #pragma unroll
                        for (int ai = 0; ai < 4; ++ai) {
                            int a = 4 * half + ai;
                            smf[ob + a * 160]      = a0[ai] * d2a;
                            smf[ob + a * 160 + 80] = a1[ai] * d2b;
                        }
                    }
                }
            }
            __syncthreads();
            // ---- P7: T3, dual-row q4 (f32 dot, f64 finish) ----
            {
                float a0 = 0.0f, a1 = 0.0f;
                #pragma unroll
                for (int jj = 0; jj < 8; ++jj) {
                    float4 uv = *reinterpret_cast<const float4*>(
                        &smf[F_U2 + aT * 160 + 40 * q + 4 * jj + 4 * (jj >> 2)]);
                    a0 += w3a[4 * jj] * uv.x + w3a[4 * jj + 1] * uv.y
                        + w3a[4 * jj + 2] * uv.z + w3a[4 * jj + 3] * uv.w;
                    a1 += w3b[4 * jj] * uv.x + w3b[4 * jj + 1] * uv.y
                        + w3b[4 * jj + 2] * uv.z + w3b[4 * jj + 3] * uv.w;
                }
                a0 = red4f(a0);
                a1 = red4f(a1);
                if (q == 0) {
                    double va = smd[D_VSIG + w * 36 + aT];
                    double2 tv;
                    tv.x = va * (double)F0 + (1.0 - (double)F0 * F0) * (double)a0;
                    tv.y = va * (double)F1 + (1.0 - (double)F1 * F1) * (double)a1;
                    *reinterpret_cast<double2*>(&smd[D_T3 + 2 * m]) = tv;
                }
            }
            __syncthreads();
            // ---- P8: combine + RK4 glue f64 (+ next CMAT) ----
            if (t < 64) {
                double g = 0.0;
                #pragma unroll
                for (int a = 0; a < 8; ++a) g += smd[D_T3 + a * 64 + t];
                double y = smd[D_YCUR + t];
                int yp = F_YB + t + 4 * (t >> 3);
                if (stage == 0)      { smd[D_KACC + t] = g;        smf[yp] = (float)(y + 0.5 * g); }
                else if (stage == 1) { smd[D_KACC + t] += 2.0 * g; smf[yp] = (float)(y + 0.5 * g); }
                else if (stage == 2) { smd[D_KACC + t] += 2.0 * g; smf[yp] = (float)(y + g); }
                else {
                    double yn = y + (smd[D_KACC + t] + g) * (1.0 / 6.0);
                    smd[D_YCUR + t] = yn;
                    smf[yp] = (float)yn;
                    smd[D_HID + (w + 1) * 64 + t] = yn;
                }
            } else if (t < 128 && stage == 3 && w < 15) {
                int idx = t - 64;
                int a = idx >> 3, bb = idx & 7;
                double cv = 0.0;
                if (a != bb) {
                    int i = a < bb ? a : bb;
                    int j = a < bb ? bb : a;
                    int pidx = 7 * i - (i * (i - 1)) / 2 + (j - i - 1);
                    double vv = smd[D_VSIG + (w + 1) * 36 + 8 + pidx];
                    cv = (a > bb) ? vv : -vv;
                }
                smf[F_CM + idx] = (float)cv;
            }
            __syncthreads();
        }
    }

    // ==== readout (f64) ====
    for (int idx = t; idx < 544; idx += NT) {
        int s = idx >> 5, oo = idx & 31;
        double acc = (double)ro_b[oo];
        const float* wr = ro_w + oo * 64;
        const double* hr = &smd[D_HID + s * 64];
        #pragma unroll
        for (int d = 0; d < 64; ++d) acc += (double)wr[d] * hr[d];
        out[(size_t)b * 544 + idx] = (float)acc;
    }
}

extern "C" void kernel_launch(void* const* d_in, const int* in_sizes, int n_in,
                              void* d_out, int out_size, void* d_ws, size_t ws_size,
                              hipStream_t stream) {
    const float* x     = (const float*)d_in[0];
    const float* ic_w1 = (const float*)d_in[1];
    const float* ic_b1 = (const float*)d_in[2];
    const float* ic_w2 = (const float*)d_in[3];
    const float* ic_b2 = (const float*)d_in[4];
    const float* ic_w3 = (const float*)d_in[5];
    const float* ic_b3 = (const float*)d_in[6];
    const float* vf_w1 = (const float*)d_in[7];
    const float* vf_b1 = (const float*)d_in[8];
    const float* vf_w2 = (const float*)d_in[9];
    const float* vf_b2 = (const float*)d_in[10];
    const float* vf_w3 = (const float*)d_in[11];
    const float* vf_b3 = (const float*)d_in[12];
    const float* ro_w  = (const float*)d_in[13];
    const float* ro_b  = (const float*)d_in[14];
    float* out = (float*)d_out;

    int B = in_sizes[0] / (257 * 8);
    hipLaunchKernelGGL(ncde_solve, dim3(B), dim3(NT), 0, stream,
                       x, ic_w1, ic_b1, ic_w2, ic_b2, ic_w3, ic_b3,
                       vf_w1, vf_b1, vf_w2, vf_b2, vf_w3, vf_b3, ro_w, ro_b, out);
}